// Round 10
// baseline (692.089 us; speedup 1.0000x reference)
//
#include <hip/hip_runtime.h>
#include <math.h>

#define BWALK 4096
#define NS 64
#define DD 256
#define NE 16
#define NSLOT 128
#define MAXBIN 1024
#define ROWBH 264            // LDS half-row stride bytes (256B bf16 + 8B pad)

typedef __attribute__((ext_vector_type(4))) float f32x4;
typedef __attribute__((ext_vector_type(8))) short s16x8;

union Frag  { s16x8 v; unsigned u[4]; uint4 q; };

__device__ inline unsigned rne_bf16(float x) {
    unsigned u = __float_as_uint(x);
    return (u + 0x7fffu + ((u >> 16) & 1u)) >> 16;
}
__device__ inline float bf16_to_f(unsigned h) { return __uint_as_float(h << 16); }

// ---------- kernel 0: two-level binning (LDS histogram, 2048 global atomics) ----------
__global__ __launch_bounds__(256) void binbuild2_kernel(
    const int* __restrict__ R, int* __restrict__ gcount, int* __restrict__ binlist)
{
    __shared__ int lcount[NSLOT];
    __shared__ int lbase[NSLOT];
    __shared__ int lrun[NSLOT];
    const int tid = threadIdx.x;
    if (tid < NSLOT) { lcount[tid] = 0; lrun[tid] = 0; }
    __syncthreads();

    const int b = blockIdx.x * 256 + tid;
    int nn[NE];
    {
        const int4* rp = (const int4*)(R + (size_t)b * NE);
        const int4 r0 = rp[0], r1 = rp[1], r2 = rp[2], r3 = rp[3];
        nn[0]=r0.x; nn[1]=r0.y; nn[2]=r0.z; nn[3]=r0.w;
        nn[4]=r1.x; nn[5]=r1.y; nn[6]=r1.z; nn[7]=r1.w;
        nn[8]=r2.x; nn[9]=r2.y; nn[10]=r2.z; nn[11]=r2.w;
        nn[12]=r3.x; nn[13]=r3.y; nn[14]=r3.z; nn[15]=r3.w;
    }
    #pragma unroll
    for (int i = 0; i < NE; ++i) atomicAdd(&lcount[nn[i]], 1);
    __syncthreads();
    if (tid < NSLOT) lbase[tid] = atomicAdd(&gcount[tid], lcount[tid]);
    __syncthreads();
    #pragma unroll
    for (int i = 0; i < NE; ++i) {
        const int r = atomicAdd(&lrun[nn[i]], 1);
        const int pos = lbase[nn[i]] + r;
        if (pos < MAXBIN) binlist[nn[i] * MAXBIN + pos] = (b << 4) | i;
    }
}

// ---------- kernel 1: binned orbital MFMA (diagnostic: tile loop x reps) ----------
__global__ __launch_bounds__(256) void orbitals2_kernel(
    const float* __restrict__ y,
    const float* __restrict__ Mup,
    const float* __restrict__ Mdn,
    const int* __restrict__ gcount,
    const int* __restrict__ binlist,
    float* __restrict__ A,
    int reps)
{
    const int n   = blockIdx.x;
    const int c   = blockIdx.y;
    const int tid = threadIdx.x;
    const int lane = tid & 63;
    const int wv   = tid >> 6;

    const int cnt = gcount[n];
    if (cnt == 0) return;

    __shared__ uint4 sBH[8 * 64];
    __shared__ uint4 sBL[8 * 64];
    __shared__ __align__(16) unsigned char sY[4 * 2 * 16 * ROWBH];

    {
        const float* Msrc = (n < NS ? Mup : Mdn) + (size_t)(n & (NS - 1)) * (DD * NE);
        #pragma unroll
        for (int pp = 0; pp < 2; ++pp) {
            const int p  = tid + pp * 256;
            const int kc = p >> 6;
            const int lt = p & 63;
            const int kg = lt >> 4;
            const int e  = lt & 15;
            unsigned h[8], l[8];
            #pragma unroll
            for (int j = 0; j < 8; ++j) {
                const float f = Msrc[(kc * 32 + kg * 8 + j) * 16 + e];
                const unsigned hh = rne_bf16(f);
                h[j] = hh;
                l[j] = rne_bf16(f - bf16_to_f(hh));
            }
            uint4 vh, vl;
            vh.x = h[0] | (h[1] << 16); vh.y = h[2] | (h[3] << 16);
            vh.z = h[4] | (h[5] << 16); vh.w = h[6] | (h[7] << 16);
            vl.x = l[0] | (l[1] << 16); vl.y = l[2] | (l[3] << 16);
            vl.z = l[4] | (l[5] << 16); vl.w = l[6] | (l[7] << 16);
            sBH[p] = vh;
            sBL[p] = vl;
        }
    }
    __syncthreads();

    const int e  = lane & 15;
    const int kg = lane >> 4;
    const int slot = n & (NS - 1);
    const int* blist = binlist + n * MAXBIN;

    char* waveBase = (char*)sY + wv * (2 * 16 * ROWBH);
    char* hiBase = waveBase;
    char* loBase = waveBase + 16 * ROWBH;

    for (int rep = 0; rep < reps; ++rep) {
        asm volatile("" ::: "memory");   // force real re-execution each rep
        for (int t = c * 4 + wv; t * 16 < cnt; t += 16) {
            const int g = t * 16;
            const int ge = g + e;
            const int myc = blist[ge < cnt ? ge : (cnt - 1)];

            f32x4 acc0 = {0.f, 0.f, 0.f, 0.f};
            f32x4 acc1 = {0.f, 0.f, 0.f, 0.f};
            f32x4 acc2 = {0.f, 0.f, 0.f, 0.f};

            #pragma unroll
            for (int h = 0; h < 2; ++h) {
                f32x4 vv[8];
                #pragma unroll
                for (int rr = 0; rr < 8; ++rr) {
                    const int rloc = 2 * rr + (lane >> 5);
                    const int code = __shfl(myc, rloc, 16);
                    const float* row = y + ((size_t)(code >> 4) * NS + slot) * DD;
                    vv[rr] = *(const f32x4*)(row + h * 128 + (lane & 31) * 4);
                }
                #pragma unroll
                for (int rr = 0; rr < 8; ++rr) {
                    unsigned hh[4], ll[4];
                    #pragma unroll
                    for (int j = 0; j < 4; ++j) {
                        const float f = vv[rr][j];
                        hh[j] = rne_bf16(f);
                        ll[j] = rne_bf16(f - bf16_to_f(hh[j]));
                    }
                    uint2 hw, lw;
                    hw.x = hh[0] | (hh[1] << 16); hw.y = hh[2] | (hh[3] << 16);
                    lw.x = ll[0] | (ll[1] << 16); lw.y = ll[2] | (ll[3] << 16);
                    const int r = 2 * rr + (lane >> 5);
                    *(uint2*)(hiBase + r * ROWBH + (lane & 31) * 8) = hw;
                    *(uint2*)(loBase + r * ROWBH + (lane & 31) * 8) = lw;
                }

                #pragma unroll
                for (int kcl = 0; kcl < 4; ++kcl) {
                    const int kc = h * 4 + kcl;
                    Frag ahi, alo, bh, bl;
                    ahi.q = *(const uint4*)(hiBase + e * ROWBH + kcl * 64 + kg * 16);
                    alo.q = *(const uint4*)(loBase + e * ROWBH + kcl * 64 + kg * 16);
                    bh.q = sBH[kc * 64 + lane];
                    bl.q = sBL[kc * 64 + lane];
                    acc0 = __builtin_amdgcn_mfma_f32_16x16x32_bf16(ahi.v, bh.v, acc0, 0, 0, 0);
                    acc1 = __builtin_amdgcn_mfma_f32_16x16x32_bf16(ahi.v, bl.v, acc1, 0, 0, 0);
                    acc2 = __builtin_amdgcn_mfma_f32_16x16x32_bf16(alo.v, bh.v, acc2, 0, 0, 0);
                }
            }
            const f32x4 acc = acc0 + (acc1 + acc2);

            #pragma unroll
            for (int r = 0; r < 4; ++r) {
                const int j = kg * 4 + r;
                const int jcode = __shfl(myc, j, 16);
                if (g + j < cnt) A[(size_t)jcode * NE + e] = acc[r];
            }
        }
    }
}

// ---------- kernel 2: batched 16x16 LU slogdet (diagnostic: body x reps) ----------
__global__ __launch_bounds__(256) void lu_det_kernel(
    const float* __restrict__ A, float* __restrict__ out, int mode, int reps)
{
    const int tid = threadIdx.x;
    const int w = blockIdx.x * 16 + (tid >> 4);
    const int lane = tid & 15;

    for (int rep = 0; rep < reps; ++rep) {
        asm volatile("" ::: "memory");
        float a[NE];
        {
            const f32x4* p = (const f32x4*)(A + ((size_t)w * NE + lane) * NE);
            #pragma unroll
            for (int q = 0; q < 4; ++q) {
                const f32x4 vv = p[q];
                a[q * 4 + 0] = vv[0]; a[q * 4 + 1] = vv[1];
                a[q * 4 + 2] = vv[2]; a[q * 4 + 3] = vv[3];
            }
        }

        unsigned used = 0u;
        float logabs = 0.0f;
        int neg = 0;
        int perm[NE];

        #pragma unroll
        for (int k = 0; k < NE; ++k) {
            float v = ((used >> lane) & 1u) ? -1.0f : fabsf(a[k]);
            int bi = lane;
            #pragma unroll
            for (int off = 8; off > 0; off >>= 1) {
                const float ov = __shfl_xor(v, off, 16);
                const int   oi = __shfl_xor(bi, off, 16);
                if (ov > v || (ov == v && oi < bi)) { v = ov; bi = oi; }
            }
            const int p = bi;
            perm[k] = p;
            const float pivval = __shfl(a[k], p, 16);
            const bool active = (((used >> lane) & 1u) == 0u) && (lane != p);
            const float mlt = active ? (a[k] / pivval) : 0.0f;
            #pragma unroll
            for (int ee = k + 1; ee < NE; ++ee) {
                const float pe = __shfl(a[ee], p, 16);
                a[ee] = fmaf(-mlt, pe, a[ee]);
            }
            used |= (1u << p);
            logabs += logf(fabsf(pivval));
            neg ^= (pivval < 0.0f) ? 1 : 0;
        }

        int inv = 0;
        #pragma unroll
        for (int k1 = 0; k1 < NE; ++k1) {
            #pragma unroll
            for (int k2 = k1 + 1; k2 < NE; ++k2)
                inv ^= (perm[k1] > perm[k2]) ? 1 : 0;
        }
        neg ^= inv;

        if (lane == 0) {
            float re = logabs;
            float im = neg ? 3.14159274101257324f : 0.0f;
            if (__builtin_isnan(re)) { re = -INFINITY; im = 0.0f; }
            else if (re == -INFINITY) { im = 0.0f; }
            if (mode == 0) { out[2 * w] = re; out[2 * w + 1] = im; }
            else           { out[w] = re; }
        }
    }
}

// ---------- fallback: round-2 fused kernel (passing, 61.5 us) ----------
__global__ __launch_bounds__(256) void outputheaddet_kernel(
    const float* __restrict__ y,
    const float* __restrict__ Mup,
    const float* __restrict__ Mdn,
    const int* __restrict__ R,
    float* __restrict__ out,
    int mode)
{
    const int b = blockIdx.x;
    const int tid = threadIdx.x;

    __shared__ int   sR[NE];
    __shared__ float sYf[NE][DD];
    __shared__ float sA[NE][NE + 1];

    if (tid < NE) sR[tid] = R[b * NE + tid];
    __syncthreads();

    {
        const int i  = tid >> 4;
        const int d0 = (tid & 15) * 16;
        const int n    = sR[i];
        const int slot = n & (NS - 1);
        const float4* yp = reinterpret_cast<const float4*>(
            y + (((size_t)b * NS + slot) * DD + d0));
        float4 v0 = yp[0], v1 = yp[1], v2 = yp[2], v3 = yp[3];
        float4* dst = reinterpret_cast<float4*>(&sYf[i][d0]);
        dst[0] = v0; dst[1] = v1; dst[2] = v2; dst[3] = v3;
    }
    __syncthreads();

    {
        const int i = tid >> 4;
        const int e = tid & 15;
        const int n    = sR[i];
        const int slot = n & (NS - 1);
        const float* Mp = (n < NS ? Mup : Mdn) + (size_t)slot * (DD * NE) + e;
        float acc = 0.0f;
        #pragma unroll 8
        for (int d = 0; d < DD; ++d)
            acc = fmaf(sYf[i][d], Mp[(size_t)d * NE], acc);
        sA[i][e] = acc;
    }
    __syncthreads();

    if (tid >= NE) return;

    const int lane = tid;
    float a[NE];
    #pragma unroll
    for (int e = 0; e < NE; ++e) a[e] = sA[lane][e];

    unsigned used = 0u;
    float logabs = 0.0f;
    int neg = 0;
    int perm[NE];

    #pragma unroll
    for (int k = 0; k < NE; ++k) {
        float v = ((used >> lane) & 1u) ? -1.0f : fabsf(a[k]);
        int bi = lane;
        #pragma unroll
        for (int off = 8; off > 0; off >>= 1) {
            float ov = __shfl_xor(v, off, 16);
            int   oi = __shfl_xor(bi, off, 16);
            if (ov > v || (ov == v && oi < bi)) { v = ov; bi = oi; }
        }
        const int p = bi;
        perm[k] = p;
        const float pivval = __shfl(a[k], p, 16);
        const bool active = (((used >> lane) & 1u) == 0u) && (lane != p);
        const float mlt = active ? (a[k] / pivval) : 0.0f;
        #pragma unroll
        for (int e2 = k + 1; e2 < NE; ++e2) {
            const float pe = __shfl(a[e2], p, 16);
            a[e2] = fmaf(-mlt, pe, a[e2]);
        }
        used |= (1u << p);
        logabs += logf(fabsf(pivval));
        neg ^= (pivval < 0.0f) ? 1 : 0;
    }

    int inv = 0;
    #pragma unroll
    for (int k1 = 0; k1 < NE; ++k1) {
        #pragma unroll
        for (int k2 = k1 + 1; k2 < NE; ++k2)
            inv ^= (perm[k1] > perm[k2]) ? 1 : 0;
    }
    neg ^= inv;

    if (lane == 0) {
        float re = logabs;
        float im = neg ? 3.14159274101257324f : 0.0f;
        if (__builtin_isnan(re)) { re = -INFINITY; im = 0.0f; }
        else if (re == -INFINITY) { im = 0.0f; }
        if (mode == 0) { out[2 * b] = re; out[2 * b + 1] = im; }
        else           { out[b] = re; }
    }
}

extern "C" void kernel_launch(void* const* d_in, const int* in_sizes, int n_in,
                              void* d_out, int out_size, void* d_ws, size_t ws_size,
                              hipStream_t stream) {
    const float* y   = (const float*)d_in[0];
    const float* Mup = (const float*)d_in[1];
    const float* Mdn = (const float*)d_in[2];
    const int*   R   = (const int*)d_in[3];
    float* out = (float*)d_out;

    const int mode = (out_size >= 2 * BWALK) ? 0 : 1;

    const size_t off_list = 1024;
    const size_t off_A    = off_list + (size_t)NSLOT * MAXBIN * sizeof(int);
    const size_t need     = off_A + (size_t)BWALK * NE * NE * sizeof(float);

    if (ws_size >= need) {
        int*   gcount  = (int*)d_ws;
        int*   binlist = (int*)((char*)d_ws + off_list);
        float* A       = (float*)((char*)d_ws + off_A);

        hipMemsetAsync(gcount, 0, NSLOT * sizeof(int), stream);
        hipLaunchKernelGGL(binbuild2_kernel, dim3(BWALK / 256), dim3(256), 0, stream,
                           R, gcount, binlist);
        // DIAGNOSTIC: orbitals x8, LU x64 (idempotent) to surface both kernels
        // in rocprof top-5 with counters; K_orb = (dur-42)/7 approx.
        hipLaunchKernelGGL(orbitals2_kernel, dim3(NSLOT, 4), dim3(256), 0, stream,
                           y, Mup, Mdn, gcount, binlist, A, 8);
        hipLaunchKernelGGL(lu_det_kernel, dim3(BWALK / 16), dim3(256), 0, stream,
                           A, out, mode, 64);
    } else {
        hipLaunchKernelGGL(outputheaddet_kernel, dim3(BWALK), dim3(256), 0, stream,
                           y, Mup, Mdn, R, out, mode);
    }
}

// Round 11
// 48.960 us; speedup vs baseline: 14.1357x; 14.1357x over previous
//
#include <hip/hip_runtime.h>
#include <math.h>

#define BWALK 4096
#define NS 64
#define DD 256
#define NE 16
#define NSLOT 128
#define MAXBIN 1024
#define ROWBH 264            // LDS half-row stride bytes (256B bf16 + 8B pad)

typedef __attribute__((ext_vector_type(4))) float f32x4;
typedef __attribute__((ext_vector_type(8))) short s16x8;

union Frag  { s16x8 v; unsigned u[4]; uint4 q; };

__device__ inline unsigned rne_bf16(float x) {
    unsigned u = __float_as_uint(x);
    return (u + 0x7fffu + ((u >> 16) & 1u)) >> 16;
}
__device__ inline float bf16_to_f(unsigned h) { return __uint_as_float(h << 16); }

// ---------- kernel 0: two-level binning (LDS histogram, 2048 global atomics) ----------
__global__ __launch_bounds__(256) void binbuild2_kernel(
    const int* __restrict__ R, int* __restrict__ gcount, int* __restrict__ binlist)
{
    __shared__ int lcount[NSLOT];
    __shared__ int lbase[NSLOT];
    __shared__ int lrun[NSLOT];
    const int tid = threadIdx.x;
    if (tid < NSLOT) { lcount[tid] = 0; lrun[tid] = 0; }
    __syncthreads();

    const int b = blockIdx.x * 256 + tid;
    int nn[NE];
    {
        const int4* rp = (const int4*)(R + (size_t)b * NE);
        const int4 r0 = rp[0], r1 = rp[1], r2 = rp[2], r3 = rp[3];
        nn[0]=r0.x; nn[1]=r0.y; nn[2]=r0.z; nn[3]=r0.w;
        nn[4]=r1.x; nn[5]=r1.y; nn[6]=r1.z; nn[7]=r1.w;
        nn[8]=r2.x; nn[9]=r2.y; nn[10]=r2.z; nn[11]=r2.w;
        nn[12]=r3.x; nn[13]=r3.y; nn[14]=r3.z; nn[15]=r3.w;
    }
    #pragma unroll
    for (int i = 0; i < NE; ++i) atomicAdd(&lcount[nn[i]], 1);
    __syncthreads();
    if (tid < NSLOT) lbase[tid] = atomicAdd(&gcount[tid], lcount[tid]);
    __syncthreads();
    #pragma unroll
    for (int i = 0; i < NE; ++i) {
        const int r = atomicAdd(&lrun[nn[i]], 1);
        const int pos = lbase[nn[i]] + r;
        if (pos < MAXBIN) binlist[nn[i] * MAXBIN + pos] = (b << 4) | i;
    }
}

// ---------- kernel 1: binned orbital MFMA ----------
__global__ __launch_bounds__(256) void orbitals2_kernel(
    const float* __restrict__ y,
    const float* __restrict__ Mup,
    const float* __restrict__ Mdn,
    const int* __restrict__ gcount,
    const int* __restrict__ binlist,
    float* __restrict__ A)
{
    const int n   = blockIdx.x;
    const int c   = blockIdx.y;
    const int tid = threadIdx.x;
    const int lane = tid & 63;
    const int wv   = tid >> 6;

    const int cnt = gcount[n];
    if (cnt == 0) return;

    __shared__ uint4 sBH[8 * 64];
    __shared__ uint4 sBL[8 * 64];
    __shared__ __align__(16) unsigned char sY[4 * 2 * 16 * ROWBH];

    {
        const float* Msrc = (n < NS ? Mup : Mdn) + (size_t)(n & (NS - 1)) * (DD * NE);
        #pragma unroll
        for (int pp = 0; pp < 2; ++pp) {
            const int p  = tid + pp * 256;
            const int kc = p >> 6;
            const int lt = p & 63;
            const int kg = lt >> 4;
            const int e  = lt & 15;
            unsigned h[8], l[8];
            #pragma unroll
            for (int j = 0; j < 8; ++j) {
                const float f = Msrc[(kc * 32 + kg * 8 + j) * 16 + e];
                const unsigned hh = rne_bf16(f);
                h[j] = hh;
                l[j] = rne_bf16(f - bf16_to_f(hh));
            }
            uint4 vh, vl;
            vh.x = h[0] | (h[1] << 16); vh.y = h[2] | (h[3] << 16);
            vh.z = h[4] | (h[5] << 16); vh.w = h[6] | (h[7] << 16);
            vl.x = l[0] | (l[1] << 16); vl.y = l[2] | (l[3] << 16);
            vl.z = l[4] | (l[5] << 16); vl.w = l[6] | (l[7] << 16);
            sBH[p] = vh;
            sBL[p] = vl;
        }
    }
    __syncthreads();

    const int e  = lane & 15;
    const int kg = lane >> 4;
    const int slot = n & (NS - 1);
    const int* blist = binlist + n * MAXBIN;

    char* waveBase = (char*)sY + wv * (2 * 16 * ROWBH);
    char* hiBase = waveBase;
    char* loBase = waveBase + 16 * ROWBH;

    for (int t = c * 4 + wv; t * 16 < cnt; t += 16) {
        const int g = t * 16;
        const int ge = g + e;
        const int myc = blist[ge < cnt ? ge : (cnt - 1)];

        f32x4 acc0 = {0.f, 0.f, 0.f, 0.f};
        f32x4 acc1 = {0.f, 0.f, 0.f, 0.f};
        f32x4 acc2 = {0.f, 0.f, 0.f, 0.f};

        #pragma unroll
        for (int h = 0; h < 2; ++h) {
            f32x4 vv[8];
            #pragma unroll
            for (int rr = 0; rr < 8; ++rr) {
                const int rloc = 2 * rr + (lane >> 5);
                const int code = __shfl(myc, rloc, 16);
                const float* row = y + ((size_t)(code >> 4) * NS + slot) * DD;
                vv[rr] = *(const f32x4*)(row + h * 128 + (lane & 31) * 4);
            }
            #pragma unroll
            for (int rr = 0; rr < 8; ++rr) {
                unsigned hh[4], ll[4];
                #pragma unroll
                for (int j = 0; j < 4; ++j) {
                    const float f = vv[rr][j];
                    hh[j] = rne_bf16(f);
                    ll[j] = rne_bf16(f - bf16_to_f(hh[j]));
                }
                uint2 hw, lw;
                hw.x = hh[0] | (hh[1] << 16); hw.y = hh[2] | (hh[3] << 16);
                lw.x = ll[0] | (ll[1] << 16); lw.y = ll[2] | (ll[3] << 16);
                const int r = 2 * rr + (lane >> 5);
                *(uint2*)(hiBase + r * ROWBH + (lane & 31) * 8) = hw;
                *(uint2*)(loBase + r * ROWBH + (lane & 31) * 8) = lw;
            }

            #pragma unroll
            for (int kcl = 0; kcl < 4; ++kcl) {
                const int kc = h * 4 + kcl;
                Frag ahi, alo, bh, bl;
                ahi.q = *(const uint4*)(hiBase + e * ROWBH + kcl * 64 + kg * 16);
                alo.q = *(const uint4*)(loBase + e * ROWBH + kcl * 64 + kg * 16);
                bh.q = sBH[kc * 64 + lane];
                bl.q = sBL[kc * 64 + lane];
                acc0 = __builtin_amdgcn_mfma_f32_16x16x32_bf16(ahi.v, bh.v, acc0, 0, 0, 0);
                acc1 = __builtin_amdgcn_mfma_f32_16x16x32_bf16(ahi.v, bl.v, acc1, 0, 0, 0);
                acc2 = __builtin_amdgcn_mfma_f32_16x16x32_bf16(alo.v, bh.v, acc2, 0, 0, 0);
            }
        }
        const f32x4 acc = acc0 + (acc1 + acc2);

        #pragma unroll
        for (int r = 0; r < 4; ++r) {
            const int j = kg * 4 + r;
            const int jcode = __shfl(myc, j, 16);
            if (g + j < cnt) A[(size_t)jcode * NE + e] = acc[r];
        }
    }
}

// ---------- kernel 2: batched 16x16 LU slogdet, 1 walker/WAVE (4x oversubscribed) ----------
// Each wave's four 16-lane groups duplicate the SAME walker (no divergence);
// 4096 waves -> 4 waves/SIMD so independent pivot chains interleave.
__global__ __launch_bounds__(256) void lu_det_kernel(
    const float* __restrict__ A, float* __restrict__ out, int mode)
{
    const int tid = threadIdx.x;
    const int w = blockIdx.x * 4 + (tid >> 6);   // one walker per wave
    const int lane = tid & 15;                    // row within the 16-lane group

    float a[NE];
    {
        const f32x4* p = (const f32x4*)(A + ((size_t)w * NE + lane) * NE);
        #pragma unroll
        for (int q = 0; q < 4; ++q) {
            const f32x4 vv = p[q];
            a[q * 4 + 0] = vv[0]; a[q * 4 + 1] = vv[1];
            a[q * 4 + 2] = vv[2]; a[q * 4 + 3] = vv[3];
        }
    }

    unsigned used = 0u;
    int neg = 0;
    int perm[NE];
    float prods[4] = {1.0f, 1.0f, 1.0f, 1.0f};   // pivot products, 4 per group

    #pragma unroll
    for (int k = 0; k < NE; ++k) {
        float v = ((used >> lane) & 1u) ? -1.0f : fabsf(a[k]);
        int bi = lane;
        #pragma unroll
        for (int off = 8; off > 0; off >>= 1) {
            const float ov = __shfl_xor(v, off, 16);
            const int   oi = __shfl_xor(bi, off, 16);
            if (ov > v || (ov == v && oi < bi)) { v = ov; bi = oi; }
        }
        const int p = bi;
        perm[k] = p;
        const float pivval = __shfl(a[k], p, 16);
        const bool active = (((used >> lane) & 1u) == 0u) && (lane != p);
        const float mlt = active ? (a[k] / pivval) : 0.0f;
        #pragma unroll
        for (int ee = k + 1; ee < NE; ++ee) {
            const float pe = __shfl(a[ee], p, 16);
            a[ee] = fmaf(-mlt, pe, a[ee]);
        }
        used |= (1u << p);
        prods[k >> 2] *= pivval;                 // static index (unrolled)
    }

    // log|det| = sum of 4 group logs; sign from group-product signs
    float logabs = 0.0f;
    #pragma unroll
    for (int g = 0; g < 4; ++g) {
        logabs += __logf(fabsf(prods[g]));
        neg ^= (prods[g] < 0.0f) ? 1 : 0;
    }

    int inv = 0;
    #pragma unroll
    for (int k1 = 0; k1 < NE; ++k1) {
        #pragma unroll
        for (int k2 = k1 + 1; k2 < NE; ++k2)
            inv ^= (perm[k1] > perm[k2]) ? 1 : 0;
    }
    neg ^= inv;

    if ((tid & 63) == 0) {                        // lane 0 of the wave writes
        float re = logabs;
        float im = neg ? 3.14159274101257324f : 0.0f;
        if (__builtin_isnan(re)) { re = -INFINITY; im = 0.0f; }
        else if (re == -INFINITY) { im = 0.0f; }
        if (mode == 0) { out[2 * w] = re; out[2 * w + 1] = im; }
        else           { out[w] = re; }
    }
}

// ---------- fallback: round-2 fused kernel (passing, 61.5 us) ----------
__global__ __launch_bounds__(256) void outputheaddet_kernel(
    const float* __restrict__ y,
    const float* __restrict__ Mup,
    const float* __restrict__ Mdn,
    const int* __restrict__ R,
    float* __restrict__ out,
    int mode)
{
    const int b = blockIdx.x;
    const int tid = threadIdx.x;

    __shared__ int   sR[NE];
    __shared__ float sYf[NE][DD];
    __shared__ float sA[NE][NE + 1];

    if (tid < NE) sR[tid] = R[b * NE + tid];
    __syncthreads();

    {
        const int i  = tid >> 4;
        const int d0 = (tid & 15) * 16;
        const int n    = sR[i];
        const int slot = n & (NS - 1);
        const float4* yp = reinterpret_cast<const float4*>(
            y + (((size_t)b * NS + slot) * DD + d0));
        float4 v0 = yp[0], v1 = yp[1], v2 = yp[2], v3 = yp[3];
        float4* dst = reinterpret_cast<float4*>(&sYf[i][d0]);
        dst[0] = v0; dst[1] = v1; dst[2] = v2; dst[3] = v3;
    }
    __syncthreads();

    {
        const int i = tid >> 4;
        const int e = tid & 15;
        const int n    = sR[i];
        const int slot = n & (NS - 1);
        const float* Mp = (n < NS ? Mup : Mdn) + (size_t)slot * (DD * NE) + e;
        float acc = 0.0f;
        #pragma unroll 8
        for (int d = 0; d < DD; ++d)
            acc = fmaf(sYf[i][d], Mp[(size_t)d * NE], acc);
        sA[i][e] = acc;
    }
    __syncthreads();

    if (tid >= NE) return;

    const int lane = tid;
    float a[NE];
    #pragma unroll
    for (int e = 0; e < NE; ++e) a[e] = sA[lane][e];

    unsigned used = 0u;
    float logabs = 0.0f;
    int neg = 0;
    int perm[NE];

    #pragma unroll
    for (int k = 0; k < NE; ++k) {
        float v = ((used >> lane) & 1u) ? -1.0f : fabsf(a[k]);
        int bi = lane;
        #pragma unroll
        for (int off = 8; off > 0; off >>= 1) {
            float ov = __shfl_xor(v, off, 16);
            int   oi = __shfl_xor(bi, off, 16);
            if (ov > v || (ov == v && oi < bi)) { v = ov; bi = oi; }
        }
        const int p = bi;
        perm[k] = p;
        const float pivval = __shfl(a[k], p, 16);
        const bool active = (((used >> lane) & 1u) == 0u) && (lane != p);
        const float mlt = active ? (a[k] / pivval) : 0.0f;
        #pragma unroll
        for (int e2 = k + 1; e2 < NE; ++e2) {
            const float pe = __shfl(a[e2], p, 16);
            a[e2] = fmaf(-mlt, pe, a[e2]);
        }
        used |= (1u << p);
        logabs += logf(fabsf(pivval));
        neg ^= (pivval < 0.0f) ? 1 : 0;
    }

    int inv = 0;
    #pragma unroll
    for (int k1 = 0; k1 < NE; ++k1) {
        #pragma unroll
        for (int k2 = k1 + 1; k2 < NE; ++k2)
            inv ^= (perm[k1] > perm[k2]) ? 1 : 0;
    }
    neg ^= inv;

    if (lane == 0) {
        float re = logabs;
        float im = neg ? 3.14159274101257324f : 0.0f;
        if (__builtin_isnan(re)) { re = -INFINITY; im = 0.0f; }
        else if (re == -INFINITY) { im = 0.0f; }
        if (mode == 0) { out[2 * b] = re; out[2 * b + 1] = im; }
        else           { out[b] = re; }
    }
}

extern "C" void kernel_launch(void* const* d_in, const int* in_sizes, int n_in,
                              void* d_out, int out_size, void* d_ws, size_t ws_size,
                              hipStream_t stream) {
    const float* y   = (const float*)d_in[0];
    const float* Mup = (const float*)d_in[1];
    const float* Mdn = (const float*)d_in[2];
    const int*   R   = (const int*)d_in[3];
    float* out = (float*)d_out;

    const int mode = (out_size >= 2 * BWALK) ? 0 : 1;

    const size_t off_list = 1024;
    const size_t off_A    = off_list + (size_t)NSLOT * MAXBIN * sizeof(int);
    const size_t need     = off_A + (size_t)BWALK * NE * NE * sizeof(float);

    if (ws_size >= need) {
        int*   gcount  = (int*)d_ws;
        int*   binlist = (int*)((char*)d_ws + off_list);
        float* A       = (float*)((char*)d_ws + off_A);

        hipMemsetAsync(gcount, 0, NSLOT * sizeof(int), stream);
        hipLaunchKernelGGL(binbuild2_kernel, dim3(BWALK / 256), dim3(256), 0, stream,
                           R, gcount, binlist);
        hipLaunchKernelGGL(orbitals2_kernel, dim3(NSLOT, 4), dim3(256), 0, stream,
                           y, Mup, Mdn, gcount, binlist, A);
        hipLaunchKernelGGL(lu_det_kernel, dim3(BWALK / 4), dim3(256), 0, stream,
                           A, out, mode);
    } else {
        hipLaunchKernelGGL(outputheaddet_kernel, dim3(BWALK), dim3(256), 0, stream,
                           y, Mup, Mdn, R, out, mode);
    }
}

// Round 12
// 41.176 us; speedup vs baseline: 16.8079x; 1.1890x over previous
//
#include <hip/hip_runtime.h>
#include <math.h>

#define BWALK 4096
#define NS 64
#define DD 256
#define NE 16
#define NSLOT 128
#define CHUNK 512            // walkers per orbitals block
#define ROWBH 264            // LDS half-row stride bytes (256B bf16 + 8B pad)

typedef __attribute__((ext_vector_type(4))) float f32x4;
typedef __attribute__((ext_vector_type(8))) short s16x8;

union Frag  { s16x8 v; unsigned u[4]; uint4 q; };

__device__ inline unsigned rne_bf16(float x) {
    unsigned u = __float_as_uint(x);
    return (u + 0x7fffu + ((u >> 16) & 1u)) >> 16;
}
__device__ inline float bf16_to_f(unsigned h) { return __uint_as_float(h << 16); }

// ---------- kernel 1: fused M-convert + slot-major gathered orbital MFMA (r8) ----------
__global__ __launch_bounds__(256) void orbitals_fused_kernel(
    const float* __restrict__ y,
    const float* __restrict__ Mup,
    const float* __restrict__ Mdn,
    const int* __restrict__ R,
    float* __restrict__ A)
{
    const int n   = blockIdx.x;            // orbital slot 0..127
    const int b0  = blockIdx.y * CHUNK;    // first walker of this chunk
    const int tid = threadIdx.x;
    const int lane = tid & 63;
    const int wv   = tid >> 6;

    __shared__ uint4 sBH[8 * 64];          // 8 KB B-frag hi: [kc][lane]
    __shared__ uint4 sBL[8 * 64];          // 8 KB B-frag lo
    __shared__ __align__(16) unsigned char sY[4 * 2 * 16 * ROWBH];  // 33 KB
    __shared__ int sCode[CHUNK];           // 2 KB compacted (b<<4)|i codes
    __shared__ int wsum[4];

    // ---- phase A: find matches (walker b matches iff n in R[b][0..15]) ----
    int m[2];
    int cnt = 0;
    #pragma unroll
    for (int q = 0; q < 2; ++q) {
        const int b = b0 + tid * 2 + q;
        const int4* rp = (const int4*)(R + (size_t)b * NE);
        int mi = -1;
        #pragma unroll
        for (int t4 = 0; t4 < 4; ++t4) {
            const int4 r4 = rp[t4];
            if (r4.x == n) mi = t4 * 4 + 0;
            if (r4.y == n) mi = t4 * 4 + 1;
            if (r4.z == n) mi = t4 * 4 + 2;
            if (r4.w == n) mi = t4 * 4 + 3;
        }
        m[q] = mi;
        cnt += (mi >= 0) ? 1 : 0;
    }

    int incl = cnt;
    #pragma unroll
    for (int off = 1; off < 64; off <<= 1) {
        const int x = __shfl_up(incl, off, 64);
        if (lane >= off) incl += x;
    }
    if (lane == 63) wsum[wv] = incl;

    // ---- phase B (pre-barrier): convert M[n] -> LDS bf16 hi/lo B-frags ----
    {
        const float* Msrc = (n < NS ? Mup : Mdn) + (size_t)(n & (NS - 1)) * (DD * NE);
        #pragma unroll
        for (int pp = 0; pp < 2; ++pp) {
            const int p  = tid + pp * 256;     // 0..511 = (kc, lane)
            const int kc = p >> 6;
            const int lt = p & 63;
            const int kg = lt >> 4;
            const int e  = lt & 15;
            unsigned h[8], l[8];
            #pragma unroll
            for (int j = 0; j < 8; ++j) {
                const float f = Msrc[(kc * 32 + kg * 8 + j) * 16 + e];
                const unsigned hh = rne_bf16(f);
                h[j] = hh;
                l[j] = rne_bf16(f - bf16_to_f(hh));
            }
            uint4 vh, vl;
            vh.x = h[0] | (h[1] << 16); vh.y = h[2] | (h[3] << 16);
            vh.z = h[4] | (h[5] << 16); vh.w = h[6] | (h[7] << 16);
            vl.x = l[0] | (l[1] << 16); vl.y = l[2] | (l[3] << 16);
            vl.z = l[4] | (l[5] << 16); vl.w = l[6] | (l[7] << 16);
            sBH[p] = vh;
            sBL[p] = vl;
        }
    }
    __syncthreads();

    int base = incl - cnt;
    #pragma unroll
    for (int w = 0; w < 3; ++w) if (w < wv) base += wsum[w];
    const int total = wsum[0] + wsum[1] + wsum[2] + wsum[3];
    {
        int p = base;
        #pragma unroll
        for (int q = 0; q < 2; ++q) {
            if (m[q] >= 0) {
                const int b = b0 + tid * 2 + q;
                sCode[p++] = (b << 4) | m[q];
            }
        }
    }
    __syncthreads();

    if (total == 0) return;

    const int e  = lane & 15;
    const int kg = lane >> 4;
    const int slot = n & (NS - 1);

    char* waveBase = (char*)sY + wv * (2 * 16 * ROWBH);
    char* hiBase = waveBase;
    char* loBase = waveBase + 16 * ROWBH;

    for (int g = wv * 16; g < total; g += 64) {
        const int gme = g + e;
        const int mycode = sCode[gme < total ? gme : (total - 1)];

        f32x4 acc0 = {0.f, 0.f, 0.f, 0.f};
        f32x4 acc1 = {0.f, 0.f, 0.f, 0.f};
        f32x4 acc2 = {0.f, 0.f, 0.f, 0.f};

        #pragma unroll
        for (int h = 0; h < 2; ++h) {
            f32x4 vv[8];
            #pragma unroll
            for (int rr = 0; rr < 8; ++rr) {
                const int idx = g + 2 * rr + (lane >> 5);
                const int code = sCode[idx < total ? idx : (total - 1)];
                const float* row = y + ((size_t)(code >> 4) * NS + slot) * DD;
                vv[rr] = *(const f32x4*)(row + h * 128 + (lane & 31) * 4);
            }
            #pragma unroll
            for (int rr = 0; rr < 8; ++rr) {
                unsigned hh[4], ll[4];
                #pragma unroll
                for (int j = 0; j < 4; ++j) {
                    const float f = vv[rr][j];
                    hh[j] = rne_bf16(f);
                    ll[j] = rne_bf16(f - bf16_to_f(hh[j]));
                }
                uint2 hw, lw;
                hw.x = hh[0] | (hh[1] << 16); hw.y = hh[2] | (hh[3] << 16);
                lw.x = ll[0] | (ll[1] << 16); lw.y = ll[2] | (ll[3] << 16);
                const int r = 2 * rr + (lane >> 5);
                *(uint2*)(hiBase + r * ROWBH + (lane & 31) * 8) = hw;
                *(uint2*)(loBase + r * ROWBH + (lane & 31) * 8) = lw;
            }

            #pragma unroll
            for (int kcl = 0; kcl < 4; ++kcl) {
                const int kc = h * 4 + kcl;
                Frag ahi, alo, bh, bl;
                ahi.q = *(const uint4*)(hiBase + e * ROWBH + kcl * 64 + kg * 16);
                alo.q = *(const uint4*)(loBase + e * ROWBH + kcl * 64 + kg * 16);
                bh.q = sBH[kc * 64 + lane];
                bl.q = sBL[kc * 64 + lane];
                acc0 = __builtin_amdgcn_mfma_f32_16x16x32_bf16(ahi.v, bh.v, acc0, 0, 0, 0);
                acc1 = __builtin_amdgcn_mfma_f32_16x16x32_bf16(ahi.v, bl.v, acc1, 0, 0, 0);
                acc2 = __builtin_amdgcn_mfma_f32_16x16x32_bf16(alo.v, bh.v, acc2, 0, 0, 0);
            }
        }
        const f32x4 acc = acc0 + (acc1 + acc2);

        // C layout: col = lane&15, row = (lane>>4)*4 + r
        #pragma unroll
        for (int r = 0; r < 4; ++r) {
            const int j = kg * 4 + r;
            const int jcode = __shfl(mycode, j, 16);
            if (g + j < total) A[(size_t)jcode * NE + e] = acc[r];
        }
    }
}

// ---------- kernel 2: LU slogdet, 1 walker/wave, readlane-based (no DS ops) ----------
// Wave's four 16-lane groups duplicate the same walker -> pivot index p is
// wave-uniform -> v_readlane (SGPR path, ~cycles) replaces ds_bpermute (~35cy).
__global__ __launch_bounds__(256) void lu_det_kernel(
    const float* __restrict__ A, float* __restrict__ out, int mode)
{
    const int tid = threadIdx.x;
    const int w = blockIdx.x * 4 + (tid >> 6);   // one walker per wave
    const int lane = tid & 15;                    // row within 16-lane group

    float a[NE];
    {
        const f32x4* p4 = (const f32x4*)(A + ((size_t)w * NE + lane) * NE);
        #pragma unroll
        for (int q = 0; q < 4; ++q) {
            const f32x4 vv = p4[q];
            a[q * 4 + 0] = vv[0]; a[q * 4 + 1] = vv[1];
            a[q * 4 + 2] = vv[2]; a[q * 4 + 3] = vv[3];
        }
    }

    unsigned used = 0u;
    int inv = 0;
    int neg = 0;
    float prods[4] = {1.0f, 1.0f, 1.0f, 1.0f};

    #pragma unroll
    for (int k = 0; k < NE; ++k) {
        // packed argmax key: high bits = |a[k]| (monotonic for +floats, low 4
        // bits masked), low 4 bits = 15-lane so ties pick the lowest lane.
        const unsigned bits = __float_as_uint(fabsf(a[k]));
        const unsigned key = ((used >> lane) & 1u) ? 0u
                            : ((bits & ~0xFu) | (15u - (unsigned)lane));
        // scalar max-tree over lanes 0..15 via readlane (no DS ops)
        unsigned kk[16];
        #pragma unroll
        for (int r = 0; r < 16; ++r)
            kk[r] = (unsigned)__builtin_amdgcn_readlane((int)key, r);
        #pragma unroll
        for (int s = 8; s > 0; s >>= 1) {
            #pragma unroll
            for (int r = 0; r < s; ++r) kk[r] = kk[r] > kk[r + s] ? kk[r] : kk[r + s];
        }
        const int p = 15 - (int)(kk[0] & 0xFu);   // wave-uniform pivot row

        const bool active = (((used >> lane) & 1u) == 0u) && (lane != p);
        inv += __popc((~used) & ((1u << p) - 1u));  // incremental inversion parity
        used |= (1u << p);

        const float pivval = __uint_as_float(
            (unsigned)__builtin_amdgcn_readlane((int)__float_as_uint(a[k]), p));
        prods[k >> 2] *= pivval;
        const float mlt = active ? (a[k] / pivval) : 0.0f;

        #pragma unroll
        for (int ee = k + 1; ee < NE; ++ee) {
            const float pe = __uint_as_float(
                (unsigned)__builtin_amdgcn_readlane((int)__float_as_uint(a[ee]), p));
            a[ee] = fmaf(-mlt, pe, a[ee]);
        }
    }

    float logabs = 0.0f;
    #pragma unroll
    for (int g = 0; g < 4; ++g) {
        logabs += __logf(fabsf(prods[g]));
        neg ^= (prods[g] < 0.0f) ? 1 : 0;
    }
    neg ^= (inv & 1);

    if ((tid & 63) == 0) {
        float re = logabs;
        float im = neg ? 3.14159274101257324f : 0.0f;
        if (__builtin_isnan(re)) { re = -INFINITY; im = 0.0f; }
        else if (re == -INFINITY) { im = 0.0f; }
        if (mode == 0) { out[2 * w] = re; out[2 * w + 1] = im; }
        else           { out[w] = re; }
    }
}

// ---------- fallback: round-2 fused kernel (passing, 61.5 us) ----------
__global__ __launch_bounds__(256) void outputheaddet_kernel(
    const float* __restrict__ y,
    const float* __restrict__ Mup,
    const float* __restrict__ Mdn,
    const int* __restrict__ R,
    float* __restrict__ out,
    int mode)
{
    const int b = blockIdx.x;
    const int tid = threadIdx.x;

    __shared__ int   sR[NE];
    __shared__ float sYf[NE][DD];
    __shared__ float sA[NE][NE + 1];

    if (tid < NE) sR[tid] = R[b * NE + tid];
    __syncthreads();

    {
        const int i  = tid >> 4;
        const int d0 = (tid & 15) * 16;
        const int n    = sR[i];
        const int slot = n & (NS - 1);
        const float4* yp = reinterpret_cast<const float4*>(
            y + (((size_t)b * NS + slot) * DD + d0));
        float4 v0 = yp[0], v1 = yp[1], v2 = yp[2], v3 = yp[3];
        float4* dst = reinterpret_cast<float4*>(&sYf[i][d0]);
        dst[0] = v0; dst[1] = v1; dst[2] = v2; dst[3] = v3;
    }
    __syncthreads();

    {
        const int i = tid >> 4;
        const int e = tid & 15;
        const int n    = sR[i];
        const int slot = n & (NS - 1);
        const float* Mp = (n < NS ? Mup : Mdn) + (size_t)slot * (DD * NE) + e;
        float acc = 0.0f;
        #pragma unroll 8
        for (int d = 0; d < DD; ++d)
            acc = fmaf(sYf[i][d], Mp[(size_t)d * NE], acc);
        sA[i][e] = acc;
    }
    __syncthreads();

    if (tid >= NE) return;

    const int lane = tid;
    float a[NE];
    #pragma unroll
    for (int e = 0; e < NE; ++e) a[e] = sA[lane][e];

    unsigned used = 0u;
    float logabs = 0.0f;
    int neg = 0;
    int perm[NE];

    #pragma unroll
    for (int k = 0; k < NE; ++k) {
        float v = ((used >> lane) & 1u) ? -1.0f : fabsf(a[k]);
        int bi = lane;
        #pragma unroll
        for (int off = 8; off > 0; off >>= 1) {
            float ov = __shfl_xor(v, off, 16);
            int   oi = __shfl_xor(bi, off, 16);
            if (ov > v || (ov == v && oi < bi)) { v = ov; bi = oi; }
        }
        const int p = bi;
        perm[k] = p;
        const float pivval = __shfl(a[k], p, 16);
        const bool active = (((used >> lane) & 1u) == 0u) && (lane != p);
        const float mlt = active ? (a[k] / pivval) : 0.0f;
        #pragma unroll
        for (int e2 = k + 1; e2 < NE; ++e2) {
            const float pe = __shfl(a[e2], p, 16);
            a[e2] = fmaf(-mlt, pe, a[e2]);
        }
        used |= (1u << p);
        logabs += logf(fabsf(pivval));
        neg ^= (pivval < 0.0f) ? 1 : 0;
    }

    int inv = 0;
    #pragma unroll
    for (int k1 = 0; k1 < NE; ++k1) {
        #pragma unroll
        for (int k2 = k1 + 1; k2 < NE; ++k2)
            inv ^= (perm[k1] > perm[k2]) ? 1 : 0;
    }
    neg ^= inv;

    if (lane == 0) {
        float re = logabs;
        float im = neg ? 3.14159274101257324f : 0.0f;
        if (__builtin_isnan(re)) { re = -INFINITY; im = 0.0f; }
        else if (re == -INFINITY) { im = 0.0f; }
        if (mode == 0) { out[2 * b] = re; out[2 * b + 1] = im; }
        else           { out[b] = re; }
    }
}

extern "C" void kernel_launch(void* const* d_in, const int* in_sizes, int n_in,
                              void* d_out, int out_size, void* d_ws, size_t ws_size,
                              hipStream_t stream) {
    const float* y   = (const float*)d_in[0];
    const float* Mup = (const float*)d_in[1];
    const float* Mdn = (const float*)d_in[2];
    const int*   R   = (const int*)d_in[3];
    float* out = (float*)d_out;

    const int mode = (out_size >= 2 * BWALK) ? 0 : 1;
    const size_t needA = (size_t)BWALK * NE * NE * sizeof(float);   // 4 MB

    if (ws_size >= needA) {
        float* A = (float*)d_ws;
        hipLaunchKernelGGL(orbitals_fused_kernel, dim3(NSLOT, BWALK / CHUNK), dim3(256), 0, stream,
                           y, Mup, Mdn, R, A);
        hipLaunchKernelGGL(lu_det_kernel, dim3(BWALK / 4), dim3(256), 0, stream,
                           A, out, mode);
    } else {
        hipLaunchKernelGGL(outputheaddet_kernel, dim3(BWALK), dim3(256), 0, stream,
                           y, Mup, Mdn, R, out, mode);
    }
}

// Round 13
// 34.871 us; speedup vs baseline: 19.8471x; 1.1808x over previous
//
#include <hip/hip_runtime.h>
#include <math.h>

#define BWALK 4096
#define NS 64
#define DD 256
#define NE 16
#define NSLOT 128
#define CHUNK 512            // walkers per orbitals block
#define ROWBH 264            // LDS half-row stride bytes (256B bf16 + 8B pad)

typedef __attribute__((ext_vector_type(4))) float f32x4;
typedef __attribute__((ext_vector_type(8))) short s16x8;

union Frag  { s16x8 v; unsigned u[4]; uint4 q; };

__device__ inline unsigned rne_bf16(float x) {
    unsigned u = __float_as_uint(x);
    return (u + 0x7fffu + ((u >> 16) & 1u)) >> 16;
}
__device__ inline float bf16_to_f(unsigned h) { return __uint_as_float(h << 16); }

// DPP row_ror rotate within each 16-lane row (CDNA row = 16 lanes), VALU-only.
#define DPP_ROR(x, n) ((unsigned)__builtin_amdgcn_update_dpp( \
        (int)(x), (int)(x), 0x120 + (n), 0xF, 0xF, false))
__device__ inline unsigned umax2(unsigned a, unsigned b) { return a > b ? a : b; }

// ---------- kernel 1: fused M-convert + slot-major gathered orbital MFMA ----------
__global__ __launch_bounds__(256) void orbitals_fused_kernel(
    const float* __restrict__ y,
    const float* __restrict__ Mup,
    const float* __restrict__ Mdn,
    const int* __restrict__ R,
    float* __restrict__ A)
{
    const int n   = blockIdx.x;            // orbital slot 0..127
    const int b0  = blockIdx.y * CHUNK;    // first walker of this chunk
    const int tid = threadIdx.x;
    const int lane = tid & 63;
    const int wv   = tid >> 6;

    __shared__ uint4 sBH[8 * 64];          // 8 KB B-frag hi: [kc][lane]
    __shared__ uint4 sBL[8 * 64];          // 8 KB B-frag lo
    __shared__ __align__(16) unsigned char sY[4 * 2 * 16 * ROWBH];  // 33 KB
    __shared__ int sCode[CHUNK];           // 2 KB compacted (b<<4)|i codes
    __shared__ int wsum[4];

    // ---- phase A: find matches (walker b matches iff n in R[b][0..15]) ----
    int m[2];
    int cnt = 0;
    #pragma unroll
    for (int q = 0; q < 2; ++q) {
        const int b = b0 + tid * 2 + q;
        const int4* rp = (const int4*)(R + (size_t)b * NE);
        int mi = -1;
        #pragma unroll
        for (int t4 = 0; t4 < 4; ++t4) {
            const int4 r4 = rp[t4];
            if (r4.x == n) mi = t4 * 4 + 0;
            if (r4.y == n) mi = t4 * 4 + 1;
            if (r4.z == n) mi = t4 * 4 + 2;
            if (r4.w == n) mi = t4 * 4 + 3;
        }
        m[q] = mi;
        cnt += (mi >= 0) ? 1 : 0;
    }

    int incl = cnt;
    #pragma unroll
    for (int off = 1; off < 64; off <<= 1) {
        const int x = __shfl_up(incl, off, 64);
        if (lane >= off) incl += x;
    }
    if (lane == 63) wsum[wv] = incl;

    // ---- phase B (pre-barrier): convert M[n] -> LDS bf16 hi/lo B-frags ----
    {
        const float* Msrc = (n < NS ? Mup : Mdn) + (size_t)(n & (NS - 1)) * (DD * NE);
        #pragma unroll
        for (int pp = 0; pp < 2; ++pp) {
            const int p  = tid + pp * 256;     // 0..511 = (kc, lane)
            const int kc = p >> 6;
            const int lt = p & 63;
            const int kg = lt >> 4;
            const int e  = lt & 15;
            unsigned h[8], l[8];
            #pragma unroll
            for (int j = 0; j < 8; ++j) {
                const float f = Msrc[(kc * 32 + kg * 8 + j) * 16 + e];
                const unsigned hh = rne_bf16(f);
                h[j] = hh;
                l[j] = rne_bf16(f - bf16_to_f(hh));
            }
            uint4 vh, vl;
            vh.x = h[0] | (h[1] << 16); vh.y = h[2] | (h[3] << 16);
            vh.z = h[4] | (h[5] << 16); vh.w = h[6] | (h[7] << 16);
            vl.x = l[0] | (l[1] << 16); vl.y = l[2] | (l[3] << 16);
            vl.z = l[4] | (l[5] << 16); vl.w = l[6] | (l[7] << 16);
            sBH[p] = vh;
            sBL[p] = vl;
        }
    }
    __syncthreads();

    int base = incl - cnt;
    #pragma unroll
    for (int w = 0; w < 3; ++w) if (w < wv) base += wsum[w];
    const int total = wsum[0] + wsum[1] + wsum[2] + wsum[3];
    {
        int p = base;
        #pragma unroll
        for (int q = 0; q < 2; ++q) {
            if (m[q] >= 0) {
                const int b = b0 + tid * 2 + q;
                sCode[p++] = (b << 4) | m[q];
            }
        }
    }
    __syncthreads();

    if (total == 0) return;

    const int e  = lane & 15;
    const int kg = lane >> 4;
    const int slot = n & (NS - 1);

    char* waveBase = (char*)sY + wv * (2 * 16 * ROWBH);
    char* hiBase = waveBase;
    char* loBase = waveBase + 16 * ROWBH;

    for (int g = wv * 16; g < total; g += 64) {
        const int gme = g + e;
        const int mycode = sCode[gme < total ? gme : (total - 1)];

        f32x4 acc0 = {0.f, 0.f, 0.f, 0.f};
        f32x4 acc1 = {0.f, 0.f, 0.f, 0.f};
        f32x4 acc2 = {0.f, 0.f, 0.f, 0.f};

        #pragma unroll
        for (int h = 0; h < 2; ++h) {
            f32x4 vv[8];
            #pragma unroll
            for (int rr = 0; rr < 8; ++rr) {
                const int idx = g + 2 * rr + (lane >> 5);
                const int code = sCode[idx < total ? idx : (total - 1)];
                const float* row = y + ((size_t)(code >> 4) * NS + slot) * DD;
                vv[rr] = *(const f32x4*)(row + h * 128 + (lane & 31) * 4);
            }
            #pragma unroll
            for (int rr = 0; rr < 8; ++rr) {
                unsigned hh[4], ll[4];
                #pragma unroll
                for (int j = 0; j < 4; ++j) {
                    const float f = vv[rr][j];
                    hh[j] = rne_bf16(f);
                    ll[j] = rne_bf16(f - bf16_to_f(hh[j]));
                }
                uint2 hw, lw;
                hw.x = hh[0] | (hh[1] << 16); hw.y = hh[2] | (hh[3] << 16);
                lw.x = ll[0] | (ll[1] << 16); lw.y = ll[2] | (ll[3] << 16);
                const int r = 2 * rr + (lane >> 5);
                *(uint2*)(hiBase + r * ROWBH + (lane & 31) * 8) = hw;
                *(uint2*)(loBase + r * ROWBH + (lane & 31) * 8) = lw;
            }

            #pragma unroll
            for (int kcl = 0; kcl < 4; ++kcl) {
                const int kc = h * 4 + kcl;
                Frag ahi, alo, bh, bl;
                ahi.q = *(const uint4*)(hiBase + e * ROWBH + kcl * 64 + kg * 16);
                alo.q = *(const uint4*)(loBase + e * ROWBH + kcl * 64 + kg * 16);
                bh.q = sBH[kc * 64 + lane];
                bl.q = sBL[kc * 64 + lane];
                acc0 = __builtin_amdgcn_mfma_f32_16x16x32_bf16(ahi.v, bh.v, acc0, 0, 0, 0);
                acc1 = __builtin_amdgcn_mfma_f32_16x16x32_bf16(ahi.v, bl.v, acc1, 0, 0, 0);
                acc2 = __builtin_amdgcn_mfma_f32_16x16x32_bf16(alo.v, bh.v, acc2, 0, 0, 0);
            }
        }
        const f32x4 acc = acc0 + (acc1 + acc2);

        // C layout: col = lane&15, row = (lane>>4)*4 + r
        #pragma unroll
        for (int r = 0; r < 4; ++r) {
            const int j = kg * 4 + r;
            const int jcode = __shfl(mycode, j, 16);
            if (g + j < total) A[(size_t)jcode * NE + e] = acc[r];
        }
    }
}

// ---------- kernel 2: LU slogdet, 4 walkers/wave, DPP argmax (no DS in argmax) ----------
__global__ __launch_bounds__(256) void lu_det_kernel(
    const float* __restrict__ A, float* __restrict__ out, int mode)
{
    const int tid = threadIdx.x;
    const int w = blockIdx.x * 16 + (tid >> 4);   // 4 walkers per wave
    const int lane = tid & 15;                     // row within 16-lane group

    float a[NE];
    {
        const f32x4* p4 = (const f32x4*)(A + ((size_t)w * NE + lane) * NE);
        #pragma unroll
        for (int q = 0; q < 4; ++q) {
            const f32x4 vv = p4[q];
            a[q * 4 + 0] = vv[0]; a[q * 4 + 1] = vv[1];
            a[q * 4 + 2] = vv[2]; a[q * 4 + 3] = vv[3];
        }
    }

    unsigned used = 0u;
    int inv = 0;
    int neg = 0;
    float prods[4] = {1.0f, 1.0f, 1.0f, 1.0f};

    #pragma unroll
    for (int k = 0; k < NE; ++k) {
        // packed argmax key (same packing r12 verified): high bits = |a[k]|,
        // low 4 bits = 15-lane (ties -> lowest lane). Masked lanes -> 0.
        const unsigned bits = __float_as_uint(fabsf(a[k]));
        unsigned key = ((used >> lane) & 1u) ? 0u
                       : ((bits & ~0xFu) | (15u - (unsigned)lane));
        // VALU-only max-reduce within the 16-lane group via DPP row_ror
        key = umax2(key, DPP_ROR(key, 8));
        key = umax2(key, DPP_ROR(key, 4));
        key = umax2(key, DPP_ROR(key, 2));
        key = umax2(key, DPP_ROR(key, 1));
        const int p = 15 - (int)(key & 0xFu);     // group-uniform pivot row

        const float pivval = __shfl(a[k], p, 16); // one bpermute
        const bool active = (((used >> lane) & 1u) == 0u) && (lane != p);
        inv += __popc((~used) & ((1u << p) - 1u));
        used |= (1u << p);
        prods[k >> 2] *= pivval;

        const float mlt = active ? (a[k] / pivval) : 0.0f;
        #pragma unroll
        for (int ee = k + 1; ee < NE; ++ee) {
            const float pe = __shfl(a[ee], p, 16); // independent, overlap
            a[ee] = fmaf(-mlt, pe, a[ee]);
        }
    }

    float logabs = 0.0f;
    #pragma unroll
    for (int g = 0; g < 4; ++g) {
        logabs += __logf(fabsf(prods[g]));
        neg ^= (prods[g] < 0.0f) ? 1 : 0;
    }
    neg ^= (inv & 1);

    if (lane == 0) {
        float re = logabs;
        float im = neg ? 3.14159274101257324f : 0.0f;
        if (__builtin_isnan(re)) { re = -INFINITY; im = 0.0f; }
        else if (re == -INFINITY) { im = 0.0f; }
        if (mode == 0) { out[2 * w] = re; out[2 * w + 1] = im; }
        else           { out[w] = re; }
    }
}

// ---------- fallback: round-2 fused kernel (passing, 61.5 us) ----------
__global__ __launch_bounds__(256) void outputheaddet_kernel(
    const float* __restrict__ y,
    const float* __restrict__ Mup,
    const float* __restrict__ Mdn,
    const int* __restrict__ R,
    float* __restrict__ out,
    int mode)
{
    const int b = blockIdx.x;
    const int tid = threadIdx.x;

    __shared__ int   sR[NE];
    __shared__ float sYf[NE][DD];
    __shared__ float sA[NE][NE + 1];

    if (tid < NE) sR[tid] = R[b * NE + tid];
    __syncthreads();

    {
        const int i  = tid >> 4;
        const int d0 = (tid & 15) * 16;
        const int n    = sR[i];
        const int slot = n & (NS - 1);
        const float4* yp = reinterpret_cast<const float4*>(
            y + (((size_t)b * NS + slot) * DD + d0));
        float4 v0 = yp[0], v1 = yp[1], v2 = yp[2], v3 = yp[3];
        float4* dst = reinterpret_cast<float4*>(&sYf[i][d0]);
        dst[0] = v0; dst[1] = v1; dst[2] = v2; dst[3] = v3;
    }
    __syncthreads();

    {
        const int i = tid >> 4;
        const int e = tid & 15;
        const int n    = sR[i];
        const int slot = n & (NS - 1);
        const float* Mp = (n < NS ? Mup : Mdn) + (size_t)slot * (DD * NE) + e;
        float acc = 0.0f;
        #pragma unroll 8
        for (int d = 0; d < DD; ++d)
            acc = fmaf(sYf[i][d], Mp[(size_t)d * NE], acc);
        sA[i][e] = acc;
    }
    __syncthreads();

    if (tid >= NE) return;

    const int lane = tid;
    float a[NE];
    #pragma unroll
    for (int e = 0; e < NE; ++e) a[e] = sA[lane][e];

    unsigned used = 0u;
    float logabs = 0.0f;
    int neg = 0;
    int perm[NE];

    #pragma unroll
    for (int k = 0; k < NE; ++k) {
        float v = ((used >> lane) & 1u) ? -1.0f : fabsf(a[k]);
        int bi = lane;
        #pragma unroll
        for (int off = 8; off > 0; off >>= 1) {
            float ov = __shfl_xor(v, off, 16);
            int   oi = __shfl_xor(bi, off, 16);
            if (ov > v || (ov == v && oi < bi)) { v = ov; bi = oi; }
        }
        const int p = bi;
        perm[k] = p;
        const float pivval = __shfl(a[k], p, 16);
        const bool active = (((used >> lane) & 1u) == 0u) && (lane != p);
        const float mlt = active ? (a[k] / pivval) : 0.0f;
        #pragma unroll
        for (int e2 = k + 1; e2 < NE; ++e2) {
            const float pe = __shfl(a[e2], p, 16);
            a[e2] = fmaf(-mlt, pe, a[e2]);
        }
        used |= (1u << p);
        logabs += logf(fabsf(pivval));
        neg ^= (pivval < 0.0f) ? 1 : 0;
    }

    int inv = 0;
    #pragma unroll
    for (int k1 = 0; k1 < NE; ++k1) {
        #pragma unroll
        for (int k2 = k1 + 1; k2 < NE; ++k2)
            inv ^= (perm[k1] > perm[k2]) ? 1 : 0;
    }
    neg ^= inv;

    if (lane == 0) {
        float re = logabs;
        float im = neg ? 3.14159274101257324f : 0.0f;
        if (__builtin_isnan(re)) { re = -INFINITY; im = 0.0f; }
        else if (re == -INFINITY) { im = 0.0f; }
        if (mode == 0) { out[2 * b] = re; out[2 * b + 1] = im; }
        else           { out[b] = re; }
    }
}

extern "C" void kernel_launch(void* const* d_in, const int* in_sizes, int n_in,
                              void* d_out, int out_size, void* d_ws, size_t ws_size,
                              hipStream_t stream) {
    const float* y   = (const float*)d_in[0];
    const float* Mup = (const float*)d_in[1];
    const float* Mdn = (const float*)d_in[2];
    const int*   R   = (const int*)d_in[3];
    float* out = (float*)d_out;

    const int mode = (out_size >= 2 * BWALK) ? 0 : 1;
    const size_t needA = (size_t)BWALK * NE * NE * sizeof(float);   // 4 MB

    if (ws_size >= needA) {
        float* A = (float*)d_ws;
        hipLaunchKernelGGL(orbitals_fused_kernel, dim3(NSLOT, BWALK / CHUNK), dim3(256), 0, stream,
                           y, Mup, Mdn, R, A);
        hipLaunchKernelGGL(lu_det_kernel, dim3(BWALK / 16), dim3(256), 0, stream,
                           A, out, mode);
    } else {
        hipLaunchKernelGGL(outputheaddet_kernel, dim3(BWALK), dim3(256), 0, stream,
                           y, Mup, Mdn, R, out, mode);
    }
}